// Round 10
// baseline (165.864 us; speedup 1.0000x reference)
//
#include <hip/hip_runtime.h>
#include <cstdint>
#include <cstddef>

#define NROWS 100000
#define FIN 512
#define HIDDEN 256
#define NCLS 50

typedef __attribute__((ext_vector_type(8))) short s16x8;
typedef __attribute__((ext_vector_type(4))) float f32x4;

// round-to-nearest-even fp32->bf16 (scalar)
__device__ __forceinline__ unsigned short f2bf(float f) {
  unsigned int u = __float_as_uint(f);
  u += 0x7fffu + ((u >> 16) & 1u);
  return (unsigned short)(u >> 16);
}

// packed fp32x2 -> bf16x2 (RNE) - single VALU op
__device__ __forceinline__ unsigned int cvt_pk_bf16(float lo, float hi) {
  unsigned int r;
  asm("v_cvt_pk_bf16_f32 %0, %1, %2" : "=v"(r) : "v"(lo), "v"(hi));
  return r;
}

__device__ __forceinline__ void gload_lds16(const void* g, void* l) {
  __builtin_amdgcn_global_load_lds(
      (const __attribute__((address_space(1))) void*)g,
      (__attribute__((address_space(3))) void*)l, 16, 0, 0);
}

__device__ __forceinline__ f32x4 mfma_bf16(s16x8 a, s16x8 b, f32x4 c) {
  return __builtin_amdgcn_mfma_f32_16x16x32_bf16(a, b, c, 0, 0, 0);
}

// prep: w1t[n][k] = bf16(W1[k][n])  [256][512]   (blocks 0..31, LDS transpose)
//       w2t[c][k] = bf16(W2[k][c]), c>=50 -> 0   [64][256]   (blocks 32..35)
__global__ __launch_bounds__(256) void prep_kernel(
    const float* __restrict__ W1, const float* __restrict__ W2,
    unsigned short* __restrict__ w1t, unsigned short* __restrict__ w2t) {
  __shared__ float tile[64][65];
  const int b = blockIdx.x, t = threadIdx.x;
  if (b < 32) {
    const int k0 = (b >> 2) * 64, n0 = (b & 3) * 64;
    const int rq = t >> 6, col = t & 63;
#pragma unroll
    for (int i = 0; i < 16; ++i) {
      int row = i * 4 + rq;
      tile[row][col] = W1[(size_t)(k0 + row) * HIDDEN + n0 + col];
    }
    __syncthreads();
#pragma unroll
    for (int i = 0; i < 16; ++i) {
      int n = i * 4 + rq;
      w1t[(size_t)(n0 + n) * FIN + k0 + col] = f2bf(tile[col][n]);
    }
  } else {
    const int b2i = b - 32;  // 0..3, k-range
#pragma unroll
    for (int i = 0; i < 16; ++i) {
      int idx = t + i * 256;          // 0..4095
      int c = idx >> 6;               // 0..63
      int k = b2i * 64 + (idx & 63);  // 0..255
      float v = (c < NCLS) ? W2[(size_t)k * NCLS + c] : 0.0f;
      w2t[(size_t)c * HIDDEN + k] = f2bf(v);
    }
  }
}

// Fused: out = log_softmax(relu(x@W1+b1) @ W2 + b2)
// 512 threads / 8 waves, tile 128 rows x 256 cols, BK=32.
// R10 structure:
//  - A: NO LDS. Per-lane global fp32 fragment loads (2x float4, 16 lines/instr)
//    ring-prefetched 2 K-steps ahead; cvt_pk to bf16 in regs.
//  - B: ring of FOUR 16KB LDS buffers via global_load_lds, staged 2 steps
//    ahead -> ONE barrier per K-step (distance-2 reuse), loads in flight
//    across barriers (compiler reg-dep vmcnt drains B(k) as a side effect:
//    B(k) is older in the VMEM queue than the A(k) regs the cvt waits on).
//  - Operand-swapped MFMA (w1-frag as A) -> epilogue b64 h-stores.
//  - Epilogue: h halves in separate 32KB LDS regions; all 8 waves run
//    write_h + GEMM2 concurrently; w2t fragments read from global (L1-hot).
__global__ __launch_bounds__(512, 4) void fused_kernel(
    const float* __restrict__ x, const unsigned short* __restrict__ w1t,
    const unsigned short* __restrict__ w2t, const float* __restrict__ b1,
    const float* __restrict__ b2, float* __restrict__ out) {
  __shared__ char smem[65536];
  unsigned short* const Bring = (unsigned short*)smem;  // 4 x 16KB ring

  const int t = threadIdx.x;
  const int lane = t & 63, wid = t >> 6;
  const int q = lane & 15, half = lane >> 4;
  const int wr = wid >> 1, wc = wid & 1;
  const int bm = blockIdx.x;

  // per-lane A row pointers (clamped tail; duplicate reads are safe)
  const float* aptr[2];
#pragma unroll
  for (int m = 0; m < 2; ++m) {
    int r = bm * 128 + wr * 32 + m * 16 + q;
    if (r > NROWS - 1) r = NROWS - 1;
    aptr[m] = x + (size_t)r * FIN + half * 8;
  }

  // B staging roles: 1024 chunks of 16B, 2/thread;
  // lds chunk (col,s) holds global chunk s^((col>>1)&3)  (R9-verified swizzle)
  const unsigned short* bsrc[2];
  int bdst[2];
#pragma unroll
  for (int i = 0; i < 2; ++i) {
    const int c = t + i * 512;
    const int col = c >> 2, s = c & 3;
    bsrc[i] = w1t + (size_t)col * FIN + ((s ^ ((col >> 1) & 3)) << 3);
    bdst[i] = c * 8;
  }

  auto stage_B = [&](int rg, int kstep) {
#pragma unroll
    for (int i = 0; i < 2; ++i)
      gload_lds16(bsrc[i] + kstep * 32, Bring + rg * 8192 + bdst[i]);
  };

  float4 ra[2][2][2];  // [slot][m][lo/hi]
  auto load_A = [&](int sl, int kstep) {
#pragma unroll
    for (int m = 0; m < 2; ++m) {
      const float* p = aptr[m] + kstep * 32;
      ra[sl][m][0] = ((const float4*)p)[0];
      ra[sl][m][1] = ((const float4*)p)[1];
    }
  };

  // acc[i][j]: i = hcol frag (8), j = xrow frag (2)
  // lane(q,half) reg r = h[xrow=(wr&1)*32+j*16+q][hcol=wc*128+i*16+4*half+r]
  f32x4 acc[8][2];
  const f32x4 z4 = {0.f, 0.f, 0.f, 0.f};
#pragma unroll
  for (int i = 0; i < 8; ++i)
#pragma unroll
    for (int j = 0; j < 2; ++j) acc[i][j] = z4;

  // prologue: B(0),B(1) DMA (older in queue than A(0),A(1) regs)
  stage_B(0, 0);
  stage_B(1, 1);
  load_A(0, 0);
  load_A(1, 1);

#pragma unroll
  for (int k = 0; k < 16; ++k) {
    const int sl = k & 1, rg = k & 3;
    if (k + 2 < 16) stage_B((k + 2) & 3, k + 2);  // 2 steps ahead

    // cvt this step's A regs (compiler vmcnt here also drains our B(k) DMA)
    s16x8 af[2];
#pragma unroll
    for (int m = 0; m < 2; ++m) {
      const float4 lo = ra[sl][m][0], hi = ra[sl][m][1];
      union { unsigned int u[4]; s16x8 v; } cvu;
      cvu.u[0] = cvt_pk_bf16(lo.x, lo.y);
      cvu.u[1] = cvt_pk_bf16(lo.z, lo.w);
      cvu.u[2] = cvt_pk_bf16(hi.x, hi.y);
      cvu.u[3] = cvt_pk_bf16(hi.z, hi.w);
      af[m] = cvu.v;
    }
    if (k + 2 < 16) load_A(sl, k + 2);  // refill ring slot, 2 ahead

    __builtin_amdgcn_sched_barrier(0);
    __builtin_amdgcn_s_barrier();       // publish B(k); distance-2 anti-dep
    __builtin_amdgcn_sched_barrier(0);

    const unsigned short* Bc = Bring + rg * 8192;
#pragma unroll
    for (int n = 0; n < 8; ++n) {
      const int col = wc * 128 + n * 16 + q;
      s16x8 bf = *(const s16x8*)(Bc + col * 32 + ((half ^ ((q >> 1) & 3)) << 3));
      // swapped: w1-frag is the A operand -> D[hcol][xrow]
      acc[n][0] = mfma_bf16(bf, af[0], acc[n][0]);
      acc[n][1] = mfma_bf16(bf, af[1], acc[n][1]);
    }
  }
  __syncthreads();  // all ring reads done before h overwrites LDS

  // ================= epilogue (all 8 waves concurrent) =================
  // h halves: waves wr<2 -> smem[0,32K), wr>=2 -> smem[32K,64K)
  unsigned short* const hls = (unsigned short*)(smem + (wr >> 1) * 32768);
#pragma unroll
  for (int i = 0; i < 8; ++i) {
    const int hc0 = wc * 128 + i * 16 + half * 4;  // 4 consecutive hcols
    const float4 b4 = *(const float4*)(b1 + hc0);
    const int ch = hc0 >> 3;
#pragma unroll
    for (int j = 0; j < 2; ++j) {
      const int rl = (wr & 1) * 32 + j * 16 + q;  // row within 64-row half
      const float v0 = fmaxf(acc[i][j][0] + b4.x, 0.0f);
      const float v1 = fmaxf(acc[i][j][1] + b4.y, 0.0f);
      const float v2 = fmaxf(acc[i][j][2] + b4.z, 0.0f);
      const float v3 = fmaxf(acc[i][j][3] + b4.w, 0.0f);
      uint2 u;
      u.x = cvt_pk_bf16(v0, v1);
      u.y = cvt_pk_bf16(v2, v3);
      const int slot = (ch + rl) & 31;  // additive swizzle
      *(uint2*)(hls + rl * 256 + slot * 8 + (half & 1) * 4) = u;
    }
  }
  __syncthreads();

  // GEMM2: wave wid -> half p=wid>>2, rows aw*16..+15; B-frags from global w2t
  const int p = wid >> 2, aw = wid & 3;
  const unsigned short* const hrd = (const unsigned short*)(smem + p * 32768);
  f32x4 acc2[4];
#pragma unroll
  for (int n = 0; n < 4; ++n) acc2[n] = z4;
  const int arl = aw * 16 + q;
#pragma unroll
  for (int j = 0; j < 8; ++j) {
    const int g = j * 4 + half;  // k-chunk index
    s16x8 a2 = *(const s16x8*)(hrd + arl * 256 + (((g + arl) & 31) << 3));
#pragma unroll
    for (int n = 0; n < 4; ++n) {
      const int c = n * 16 + q;
      s16x8 b2f = *(const s16x8*)(w2t + (size_t)c * HIDDEN + j * 32 + half * 8);
      acc2[n] = mfma_bf16(a2, b2f, acc2[n]);
    }
  }

  float bias2[4];
#pragma unroll
  for (int n = 0; n < 4; ++n) {
    const int c = n * 16 + q;
    bias2[n] = (c < NCLS) ? b2[c] : 0.0f;
  }
#pragma unroll
  for (int r = 0; r < 4; ++r) {
    float vals[4];
    float mx = -1e30f;
#pragma unroll
    for (int n = 0; n < 4; ++n) {
      const int c = n * 16 + q;
      float v = acc2[n][r] + bias2[n];
      vals[n] = v;
      if (c < NCLS) mx = fmaxf(mx, v);
    }
    for (int off = 8; off >= 1; off >>= 1)
      mx = fmaxf(mx, __shfl_xor(mx, off, 64));
    float s = 0.f;
#pragma unroll
    for (int n = 0; n < 4; ++n) {
      const int c = n * 16 + q;
      if (c < NCLS) s += __expf(vals[n] - mx);
    }
    for (int off = 8; off >= 1; off >>= 1) s += __shfl_xor(s, off, 64);
    const float lz = __logf(s);
    const int rowg = bm * 128 + p * 64 + aw * 16 + half * 4 + r;
    if (rowg < NROWS) {
#pragma unroll
      for (int n = 0; n < 4; ++n) {
        const int c = n * 16 + q;
        if (c < NCLS) out[(size_t)rowg * NCLS + c] = vals[n] - mx - lz;
      }
    }
  }
}

extern "C" void kernel_launch(void* const* d_in, const int* in_sizes, int n_in,
                              void* d_out, int out_size, void* d_ws, size_t ws_size,
                              hipStream_t stream) {
  const float* x  = (const float*)d_in[0];
  // d_in[1] = edge_index: dead (ALPHA==1.0 makes APPNP the identity)
  const float* W1 = (const float*)d_in[2];
  const float* b1 = (const float*)d_in[3];
  const float* W2 = (const float*)d_in[4];
  const float* b2 = (const float*)d_in[5];
  float* out = (float*)d_out;

  char* ws = (char*)d_ws;
  unsigned short* w1t = (unsigned short*)(ws);           // 256 KB
  unsigned short* w2t = (unsigned short*)(ws + 262144);  // 32 KB

  prep_kernel<<<36, 256, 0, stream>>>(W1, W2, w1t, w2t);
  fused_kernel<<<(NROWS + 127) / 128, 512, 0, stream>>>(x, w1t, w2t, b1, b2, out);
}

// Round 11
// 81.230 us; speedup vs baseline: 2.0419x; 2.0419x over previous
//
#include <hip/hip_runtime.h>
#include <cstdint>
#include <cstddef>

#define NROWS 100000
#define FIN 512
#define HIDDEN 256
#define NCLS 50

typedef __attribute__((ext_vector_type(8))) short s16x8;
typedef __attribute__((ext_vector_type(4))) float f32x4;
typedef __attribute__((ext_vector_type(16))) float f32x16;

// round-to-nearest-even fp32->bf16 (scalar)
__device__ __forceinline__ unsigned short f2bf(float f) {
  unsigned int u = __float_as_uint(f);
  u += 0x7fffu + ((u >> 16) & 1u);
  return (unsigned short)(u >> 16);
}

// packed fp32x2 -> bf16x2 (RNE) - single VALU op
__device__ __forceinline__ unsigned int cvt_pk_bf16(float lo, float hi) {
  unsigned int r;
  asm("v_cvt_pk_bf16_f32 %0, %1, %2" : "=v"(r) : "v"(lo), "v"(hi));
  return r;
}

__device__ __forceinline__ void gload_lds16(const void* g, void* l) {
  __builtin_amdgcn_global_load_lds(
      (const __attribute__((address_space(1))) void*)g,
      (__attribute__((address_space(3))) void*)l, 16, 0, 0);
}

__device__ __forceinline__ f32x4 mfma_bf16(s16x8 a, s16x8 b, f32x4 c) {
  return __builtin_amdgcn_mfma_f32_16x16x32_bf16(a, b, c, 0, 0, 0);
}
__device__ __forceinline__ f32x16 mfma32(s16x8 a, s16x8 b, f32x16 c) {
  return __builtin_amdgcn_mfma_f32_32x32x16_bf16(a, b, c, 0, 0, 0);
}

// prep: w1t[n][k] = bf16(W1[k][n])  [256][512]   (blocks 0..31, LDS transpose)
//       w2t[c][k] = bf16(W2[k][c]), c>=50 -> 0   [64][256]   (blocks 32..35)
__global__ __launch_bounds__(256) void prep_kernel(
    const float* __restrict__ W1, const float* __restrict__ W2,
    unsigned short* __restrict__ w1t, unsigned short* __restrict__ w2t) {
  __shared__ float tile[64][65];
  const int b = blockIdx.x, t = threadIdx.x;
  if (b < 32) {
    const int k0 = (b >> 2) * 64, n0 = (b & 3) * 64;
    const int rq = t >> 6, col = t & 63;
#pragma unroll
    for (int i = 0; i < 16; ++i) {
      int row = i * 4 + rq;
      tile[row][col] = W1[(size_t)(k0 + row) * HIDDEN + n0 + col];
    }
    __syncthreads();
#pragma unroll
    for (int i = 0; i < 16; ++i) {
      int n = i * 4 + rq;
      w1t[(size_t)(n0 + n) * FIN + k0 + col] = f2bf(tile[col][n]);
    }
  } else {
    const int b2i = b - 32;  // 0..3, k-range
#pragma unroll
    for (int i = 0; i < 16; ++i) {
      int idx = t + i * 256;          // 0..4095
      int c = idx >> 6;               // 0..63
      int k = b2i * 64 + (idx & 63);  // 0..255
      float v = (c < NCLS) ? W2[(size_t)k * NCLS + c] : 0.0f;
      w2t[(size_t)c * HIDDEN + k] = f2bf(v);
    }
  }
}

// Fused: out = log_softmax(relu(x@W1+b1) @ W2 + b2)
// R11: 512 thr / 8 waves (2 row-groups x 4 col-groups), tile 128x256, BK=32,
// GEMM1 in 32x32x16 MFMA (64x64 wave tiles -> B re-read 2x not 4x).
// A: x fp32 -> regs (1 step ahead) -> cvt_pk bf16 -> ds_write_b128 into
//    [128 rows][4 slots] bf16 tile, slot = ks ^ ((row>>1)&3). 2 x 8KB.
// B: w1t via global_load_lds, R9 swizzle (s ^ ((col>>1)&3)). 2 x 16KB.
// One __syncthreads per K-step (stage->compute->barrier; DMA lands during
// compute). Operand-swapped MFMA (w1 = A-op) -> epilogue b64 h-stores.
// Epilogue: concurrent halves (R10's verified layout), w2t from global.
__global__ __launch_bounds__(512, 4) void fused_kernel(
    const float* __restrict__ x, const unsigned short* __restrict__ w1t,
    const unsigned short* __restrict__ w2t, const float* __restrict__ b1,
    const float* __restrict__ b2, float* __restrict__ out) {
  __shared__ char smem[65536];
  unsigned short* const Abase = (unsigned short*)smem;            // 2 x 8KB bf16
  unsigned short* const Bbase = (unsigned short*)(smem + 16384);  // 2 x 16KB bf16

  const int t = threadIdx.x;
  const int lane = t & 63, wid = t >> 6;
  const int q = lane & 15, half = lane >> 4;   // epilogue/gemm2 (16x16)
  const int l31 = lane & 31, l5 = lane >> 5;   // 32x32 frags
  const int wrow = wid >> 2, wcol = wid & 3;
  const int bm = blockIdx.x;

  // ---- A staging role: thread t -> (row = t>>2, k-chunk ks = t&3 of 8 f32) ----
  const int arow = t >> 2, aks = t & 3;
  int grow = bm * 128 + arow;
  if (grow > NROWS - 1) grow = NROWS - 1;  // tail clamp (duplicate reads safe)
  const float* const asrc = x + (size_t)grow * FIN + aks * 8;
  unsigned short* const adst =
      Abase + arow * 32 + (aks ^ ((arow >> 1) & 3)) * 8;

  float4 ra0, ra1;
  auto load_A = [&](int k0) {
    ra0 = ((const float4*)(asrc + k0))[0];
    ra1 = ((const float4*)(asrc + k0))[1];
  };
  auto write_A = [&](int buf) {
    uint4 u;
    u.x = cvt_pk_bf16(ra0.x, ra0.y);
    u.y = cvt_pk_bf16(ra0.z, ra0.w);
    u.z = cvt_pk_bf16(ra1.x, ra1.y);
    u.w = cvt_pk_bf16(ra1.z, ra1.w);
    *(uint4*)(adst + buf * 4096) = u;
  };

  // ---- B staging: 1024 chunks of 16B, 2/thread; lds slot s of col holds
  //      global chunk s ^ ((col>>1)&3)  (R9-verified) ----
  const unsigned short* bsrc[2];
  int bdst[2];
#pragma unroll
  for (int i = 0; i < 2; ++i) {
    const int c = t + i * 512;
    const int col = c >> 2, s = c & 3;
    bsrc[i] = w1t + (size_t)col * FIN + ((s ^ ((col >> 1) & 3)) << 3);
    bdst[i] = c * 8;
  }
  auto stage_B = [&](int buf, int k0) {
#pragma unroll
    for (int i = 0; i < 2; ++i)
      gload_lds16(bsrc[i] + k0, Bbase + buf * 8192 + bdst[i]);
  };

  // acc[i][j]: i = hcol frag (2 x 32 cols), j = xrow frag (2 x 32 rows)
  // D: xrow = j*32 + l31, hcol = i*32 + (r&3) + 8*(r>>2) + 4*l5
  f32x16 acc[2][2];
#pragma unroll
  for (int i = 0; i < 2; ++i)
#pragma unroll
    for (int j = 0; j < 2; ++j)
#pragma unroll
      for (int r = 0; r < 16; ++r) acc[i][j][r] = 0.0f;

  // prologue
  stage_B(0, 0);
  load_A(0);
  write_A(0);     // compiler waits our A loads (drains B(0) DMA too; once)
  load_A(32);     // step-1 A into regs
  __syncthreads();

  for (int ks = 0; ks < 16; ++ks) {
    const int cur = ks & 1;
    if (ks < 15) stage_B(cur ^ 1, (ks + 1) * 32);  // DMA lands during compute

    const unsigned short* Ac = Abase + cur * 4096;
    const unsigned short* Bc = Bbase + cur * 8192;
    s16x8 af[2][2], xf[2][2];  // [ksub][frag]
#pragma unroll
    for (int ksub = 0; ksub < 2; ++ksub) {
      const int sl = ksub * 2 + l5;
#pragma unroll
      for (int i = 0; i < 2; ++i) {
        const int col = wcol * 64 + i * 32 + l31;
        af[ksub][i] =
            *(const s16x8*)(Bc + col * 32 + ((sl ^ ((col >> 1) & 3)) << 3));
      }
#pragma unroll
      for (int j = 0; j < 2; ++j) {
        const int row = wrow * 64 + j * 32 + l31;
        xf[ksub][j] =
            *(const s16x8*)(Ac + row * 32 + ((sl ^ ((row >> 1) & 3)) << 3));
      }
    }
#pragma unroll
    for (int ksub = 0; ksub < 2; ++ksub)
#pragma unroll
      for (int i = 0; i < 2; ++i)
#pragma unroll
        for (int j = 0; j < 2; ++j)
          acc[i][j] = mfma32(af[ksub][i], xf[ksub][j], acc[i][j]);

    if (ks < 15) {
      write_A(cur ^ 1);                       // A(ks+1) -> LDS (regs from last step)
      if (ks < 14) load_A((ks + 2) * 32);     // refill regs for step ks+2
    }
    __syncthreads();  // reads of cur done everywhere; cur^1 fully staged
  }

  // ================= epilogue (all 8 waves concurrent) =================
  // h halves: rows 0..63 -> smem[0,32K), 64..127 -> smem[32K,64K).
  // element (rl, hcol) at rl*256 + ((hcol>>3 + rl)&31)*8 + (hcol&7)  [ushort]
  unsigned short* const hls = (unsigned short*)(smem + wrow * 32768);
#pragma unroll
  for (int i = 0; i < 2; ++i) {
#pragma unroll
    for (int rq = 0; rq < 4; ++rq) {
      const int hb = wcol * 64 + i * 32 + 8 * rq + 4 * l5;  // 4 consec hcols
      const float4 b4 = *(const float4*)(b1 + hb);
      const int ch = hb >> 3;
#pragma unroll
      for (int j = 0; j < 2; ++j) {
        const int rl = j * 32 + l31;
        const float v0 = fmaxf(acc[i][j][rq * 4 + 0] + b4.x, 0.0f);
        const float v1 = fmaxf(acc[i][j][rq * 4 + 1] + b4.y, 0.0f);
        const float v2 = fmaxf(acc[i][j][rq * 4 + 2] + b4.z, 0.0f);
        const float v3 = fmaxf(acc[i][j][rq * 4 + 3] + b4.w, 0.0f);
        uint2 u;
        u.x = cvt_pk_bf16(v0, v1);
        u.y = cvt_pk_bf16(v2, v3);
        const int slot = (ch + rl) & 31;
        *(uint2*)(hls + rl * 256 + slot * 8 + (hb & 7)) = u;
      }
    }
  }
  __syncthreads();

  // GEMM2 (16x16x32): wave wid -> half p=wid>>2, rows aw*16..+15;
  // B-frags from global w2t (32KB, L1-hot, identical across waves).
  const int p = wid >> 2, aw = wid & 3;
  const unsigned short* const hrd = (const unsigned short*)(smem + p * 32768);
  f32x4 acc2[4];
  const f32x4 z4 = {0.f, 0.f, 0.f, 0.f};
#pragma unroll
  for (int n = 0; n < 4; ++n) acc2[n] = z4;
  const int arl = aw * 16 + q;
#pragma unroll
  for (int j = 0; j < 8; ++j) {
    const int g = j * 4 + half;  // k-chunk index
    s16x8 a2 = *(const s16x8*)(hrd + arl * 256 + (((g + arl) & 31) << 3));
#pragma unroll
    for (int n = 0; n < 4; ++n) {
      const int c = n * 16 + q;
      s16x8 b2f = *(const s16x8*)(w2t + (size_t)c * HIDDEN + j * 32 + half * 8);
      acc2[n] = mfma_bf16(a2, b2f, acc2[n]);
    }
  }

  float bias2[4];
#pragma unroll
  for (int n = 0; n < 4; ++n) {
    const int c = n * 16 + q;
    bias2[n] = (c < NCLS) ? b2[c] : 0.0f;
  }
#pragma unroll
  for (int r = 0; r < 4; ++r) {
    float vals[4];
    float mx = -1e30f;
#pragma unroll
    for (int n = 0; n < 4; ++n) {
      const int c = n * 16 + q;
      float v = acc2[n][r] + bias2[n];
      vals[n] = v;
      if (c < NCLS) mx = fmaxf(mx, v);
    }
    for (int off = 8; off >= 1; off >>= 1)
      mx = fmaxf(mx, __shfl_xor(mx, off, 64));
    float s = 0.f;
#pragma unroll
    for (int n = 0; n < 4; ++n) {
      const int c = n * 16 + q;
      if (c < NCLS) s += __expf(vals[n] - mx);
    }
    for (int off = 8; off >= 1; off >>= 1) s += __shfl_xor(s, off, 64);
    const float lz = __logf(s);
    const int rowg = bm * 128 + p * 64 + aw * 16 + half * 4 + r;
    if (rowg < NROWS) {
#pragma unroll
      for (int n = 0; n < 4; ++n) {
        const int c = n * 16 + q;
        if (c < NCLS) out[(size_t)rowg * NCLS + c] = vals[n] - mx - lz;
      }
    }
  }
}

extern "C" void kernel_launch(void* const* d_in, const int* in_sizes, int n_in,
                              void* d_out, int out_size, void* d_ws, size_t ws_size,
                              hipStream_t stream) {
  const float* x  = (const float*)d_in[0];
  // d_in[1] = edge_index: dead (ALPHA==1.0 makes APPNP the identity)
  const float* W1 = (const float*)d_in[2];
  const float* b1 = (const float*)d_in[3];
  const float* W2 = (const float*)d_in[4];
  const float* b2 = (const float*)d_in[5];
  float* out = (float*)d_out;

  char* ws = (char*)d_ws;
  unsigned short* w1t = (unsigned short*)(ws);           // 256 KB
  unsigned short* w2t = (unsigned short*)(ws + 262144);  // 32 KB

  prep_kernel<<<36, 256, 0, stream>>>(W1, W2, w1t, w2t);
  fused_kernel<<<(NROWS + 127) / 128, 512, 0, stream>>>(x, w1t, w2t, b1, b2, out);
}